// Round 5
// baseline (103.096 us; speedup 1.0000x reference)
//
#include <hip/hip_runtime.h>

#define NQ 32768
#define NC 8192
#define CFEAT 128
#define CSPLIT 64
#define TILE (NC / CSPLIT)   // 128 coords per split
#define BLK 256
#define QPT 8                // queries per thread (phase 1)
#define QPB (BLK * QPT)      // 2048 queries per block
#define GX (NQ / QPB)        // 16 -> phase-1 grid (16, 64) = 1024 blocks
#define QB2 64               // queries per block (phase 2) -> 512 blocks
#define QPW2 (QB2 / 4)       // 16 queries per wave (phase 2)

// ws layout: [0, 8 MB) f32 bestd[CSPLIT][NQ]  (TRANSPOSED: phase-1 stores and
// phase-2 reduce reads are both perfectly coalesced); then float4 ctab[NC].
//
// NUMERICS IS FROZEN (R3/R4 lesson): the distance chain MUST be exactly
//   t = mul(cx', px); t = fma(cy', py, t); t = fma(cz', pz, t); d = cc + t
// with ctab entry (-2cx, -2cy, -2cz, ((cx*cx + cy*cy) + cz*cz)).
// This chain is empirically flip-free vs np's argmin on this dataset
// (R0/R2: absmax == 0.0 bit-exact). The 3-fma variant
// d = fma(cx',px, fma(cy',py, fma(cz',pz, cc))) flips >=1 near-tie query
// (R3/R4: identical absmax 4.047 across different structures). Top-2 gaps
// here have mass at the ~1-ulp scale — do not touch the chain again.
//
// ctab is written by phase 1 (blockIdx.x==0 blocks) and read by phase 2 —
// both phases consume the SAME stored bits (R1 lesson: -ffp-contract=fast
// may fuse the cc formula differently per compilation; share bits, don't
// recompute). Cross-kernel visibility: guaranteed by the kernel boundary.
#define BESTD_OFF 0
#define CTAB_OFF ((size_t)NQ * CSPLIT * 4)

// Phase 1: per-split min DISTANCE only — no index tracking.
// min3-paired: {mul,fma,fma,add} x2 + v_min3_f32 = 9 VALU / 2 coords / query
// -> ~15.3 us VALU floor at 78.6 T lane-ops/s.
__global__ __launch_bounds__(BLK, 4) void argmin_split(
    const float* __restrict__ coords, const float* __restrict__ points,
    float* __restrict__ bestd, float4* __restrict__ ctab) {
  __shared__ float4 ctab_s[TILE];

  const int s = blockIdx.y;
  const int base = s * TILE;

  if (threadIdx.x < TILE) {
    const int i = base + threadIdx.x;
    const float cx = coords[i * 3 + 0];
    const float cy = coords[i * 3 + 1];
    const float cz = coords[i * 3 + 2];
    float xx = cx * cx, yy = cy * cy, zz = cz * cz;
    // Opaque barrier: forbid contracting these products into the adds.
    asm volatile("" : "+v"(xx), "+v"(yy), "+v"(zz));
    const float cc = (xx + yy) + zz;
    const float4 e = make_float4(-2.0f * cx, -2.0f * cy, -2.0f * cz, cc);
    ctab_s[threadIdx.x] = e;
    if (blockIdx.x == 0) ctab[i] = e;   // persist exact bits for phase 2
  }

  const int q0 = blockIdx.x * QPB + threadIdx.x;
  float px[QPT], py[QPT], pz[QPT], best[QPT];
  #pragma unroll
  for (int k = 0; k < QPT; ++k) {
    const int q = q0 + k * BLK;
    px[k] = points[q * 3 + 0];
    py[k] = points[q * 3 + 1];
    pz[k] = points[q * 3 + 2];
    best[k] = __builtin_inff();
  }
  __syncthreads();

  #pragma unroll 2
  for (int i = 0; i < TILE; i += 2) {
    const float4 c0 = ctab_s[i];     // uniform addr -> broadcast ds_read_b128
    const float4 c1 = ctab_s[i + 1];
    #pragma unroll
    for (int k = 0; k < QPT; ++k) {
      float t0 = __fmul_rn(c0.x, px[k]);            // FROZEN CHAIN (R2)
      t0 = __fmaf_rn(c0.y, py[k], t0);
      t0 = __fmaf_rn(c0.z, pz[k], t0);
      const float d0 = __fadd_rn(c0.w, t0);
      float t1 = __fmul_rn(c1.x, px[k]);
      t1 = __fmaf_rn(c1.y, py[k], t1);
      t1 = __fmaf_rn(c1.z, pz[k], t1);
      const float d1 = __fadd_rn(c1.w, t1);
      best[k] = fminf(fminf(best[k], d0), d1);      // v_min3_f32 (exact)
    }
  }

  // Transposed store: consecutive q across the wave -> coalesced 256 B.
  #pragma unroll
  for (int k = 0; k < QPT; ++k) {
    bestd[(size_t)s * NQ + q0 + k * BLK] = best[k];
  }
}

// Phase 2: per block of 64 queries —
//  (2a) threads 0..63, lane-per-query: min+first-argmin over the 64 splits,
//       reading bestd[s][q0+l] (coalesced). Strict `v < m` keeps the FIRST
//       split attaining the min. Park (m, sstar) in LDS.
//  (2b) 4 waves x 16 queries, wave-per-query: equality-rescan the winning
//       split's 128 coords from global ctab (same bits + same frozen chain
//       as phase 1 -> hit guaranteed; ballot/ffs -> lowest coord index), then
//       gather the 128-float feature row with 64 lanes x float2.
// Tiebreak chain: first split attaining global min, then first coord within
// it == np.argmin's global first-index.
__global__ __launch_bounds__(BLK) void reduce_rescan_gather(
    const float4* __restrict__ ctab, const float* __restrict__ points,
    const float* __restrict__ bestd, const float* __restrict__ feature,
    float2* __restrict__ out) {
  __shared__ float ms[QB2];
  __shared__ int ssi[QB2];

  const int q0 = blockIdx.x * QB2;
  const int tid = threadIdx.x;

  if (tid < QB2) {
    const int q = q0 + tid;
    float m = __builtin_inff();
    int ss = 0;
    #pragma unroll
    for (int s = 0; s < CSPLIT; ++s) {
      const float v = bestd[(size_t)s * NQ + q];
      if (v < m) ss = s;        // strict: first split attaining min wins
      m = fminf(m, v);
    }
    ms[tid] = m;
    ssi[tid] = ss;
  }
  __syncthreads();

  const int w = tid >> 6;
  const int l = tid & 63;

  for (int j = 0; j < QPW2; ++j) {
    const int qi = w * QPW2 + j;            // uniform within the wave
    const int q = q0 + qi;
    const float m = ms[qi];                 // LDS broadcast
    const int b2 = ssi[qi] * TILE;

    const float qx = points[q * 3 + 0];     // wave-uniform
    const float qy = points[q * 3 + 1];
    const float qz = points[q * 3 + 2];

    const float4 c0 = ctab[b2 + l];         // coalesced, lanes consecutive
    const float4 c1 = ctab[b2 + 64 + l];
    float t0 = __fmul_rn(c0.x, qx);                 // FROZEN CHAIN (R2)
    t0 = __fmaf_rn(c0.y, qy, t0);
    t0 = __fmaf_rn(c0.z, qz, t0);
    const float d0 = __fadd_rn(c0.w, t0);
    float t1 = __fmul_rn(c1.x, qx);
    t1 = __fmaf_rn(c1.y, qy, t1);
    t1 = __fmaf_rn(c1.z, qz, t1);
    const float d1 = __fadd_rn(c1.w, t1);

    const unsigned long long b0 = __ballot(d0 == m);
    const unsigned long long b1 = __ballot(d1 == m);
    int off_in;
    if (b0 | b1) {
      off_in = b0 ? (__ffsll(b0) - 1) : (64 + __ffsll(b1) - 1);
    } else {
      // Defense in depth (should be unreachable): true argmin over the 128
      // rescanned candidates, first-index tiebreak.
      float dm = fminf(d0, d1);
      int im = (d0 <= d1) ? l : (64 + l);
      #pragma unroll
      for (int off = 32; off; off >>= 1) {
        const float od = __shfl_xor(dm, off, 64);
        const int oi = __shfl_xor(im, off, 64);
        if (od < dm || (od == dm && oi < im)) { dm = od; im = oi; }
      }
      off_in = im;
    }
    const int idx = b2 + off_in;

    const float2* fr = (const float2*)(feature + (size_t)idx * CFEAT);
    out[(size_t)q * (CFEAT / 2) + l] = fr[l];
  }
}

extern "C" void kernel_launch(void* const* d_in, const int* in_sizes, int n_in,
                              void* d_out, int out_size, void* d_ws, size_t ws_size,
                              hipStream_t stream) {
  const float* coords  = (const float*)d_in[0];   // [8192, 3]
  const float* feature = (const float*)d_in[1];   // [8192, 128]
  const float* points  = (const float*)d_in[2];   // [32768, 3]
  float2* out = (float2*)d_out;                   // [32768, 128]

  float* bestd = (float*)((char*)d_ws + BESTD_OFF);
  float4* ctab = (float4*)((char*)d_ws + CTAB_OFF);

  dim3 grid1(GX, CSPLIT);                         // (16, 64) = 1024 blocks
  argmin_split<<<grid1, BLK, 0, stream>>>(coords, points, bestd, ctab);

  reduce_rescan_gather<<<NQ / QB2, BLK, 0, stream>>>(ctab, points, bestd,
                                                     feature, out);
}

// Round 6
// 97.956 us; speedup vs baseline: 1.0525x; 1.0525x over previous
//
#include <hip/hip_runtime.h>

#define NQ 32768
#define NC 8192
#define CFEAT 128
#define CSPLIT 64
#define TILE (NC / CSPLIT)   // 128 coords per split
#define BLK 256
#define QPT 4                // queries per thread (phase 1)
#define QPB (BLK * QPT)      // 1024 queries per block
#define GX (NQ / QPB)        // 32 -> phase-1 grid (32, 64) = 2048 blocks

// ws layout: [0, 8 MB) f32 bestd[NQ][CSPLIT] ([q][s]: phase-2 wave reads one
// 256 B row per query — R2-proven; phase-1 scatter-stores are L2-absorbed);
// then float4 ctab[NC] (128 KB).
//
// NUMERICS IS FROZEN (R3/R4 lesson): the distance chain MUST be exactly
//   t = mul(cx', px); t = fma(cy', py, t); t = fma(cz', pz, t); d = cc + t
// with ctab entry (-2cx, -2cy, -2cz, ((cx*cx + cy*cy) + cz*cz)).
// This chain is empirically flip-free vs np's argmin (R0/R2/R5: absmax 0.0).
// The 3-fma variant flips near-tie queries (R3/R4: identical absmax 4.047).
// R6 packs coord PAIRS into v_pk_{mul,fma,add}_f32 — each packed half is the
// same IEEE-RN op sequence, so bits are unchanged whether the compiler emits
// pk or scalarizes. Phase 2 consumes the SAME stored ctab bits (R1 lesson).
//
// STRUCTURE LESSON (R5): phase 2 must stay wave-per-query with 32768 waves —
// TLP beats coalescing polish for short latency-bound phases.
#define BESTD_OFF 0
#define CTAB_OFF ((size_t)NQ * CSPLIT * 4)

typedef float f32x2 __attribute__((ext_vector_type(2)));

// Phase 1: per-split min DISTANCE only — no index tracking.
// Packed inner loop: per 2 coords per query
//   v_pk_mul + v_pk_fma + v_pk_fma + v_pk_add + v_min3 = 5 insts (was 9)
// -> 8.6 us issue floor at 2 cyc/inst/SIMD.
__global__ __launch_bounds__(BLK, 4) void argmin_split(
    const float* __restrict__ coords, const float* __restrict__ points,
    float* __restrict__ bestd, float4* __restrict__ ctab) {
  // Pair-interleaved LDS ctab: A[p]=(x0,x1,y0,y1), B[p]=(z0,z1,w0,w1) for
  // coords (base+2p, base+2p+1). One b128 read each; halves are aligned
  // VGPR pairs -> direct v_pk operands.
  __shared__ float4 sA[TILE / 2];
  __shared__ float4 sB[TILE / 2];

  const int s = blockIdx.y;
  const int base = s * TILE;

  if (threadIdx.x < TILE) {
    const int i = base + threadIdx.x;
    const float cx = coords[i * 3 + 0];
    const float cy = coords[i * 3 + 1];
    const float cz = coords[i * 3 + 2];
    float xx = cx * cx, yy = cy * cy, zz = cz * cz;
    // Opaque barrier: forbid contracting these products into the adds.
    asm volatile("" : "+v"(xx), "+v"(yy), "+v"(zz));
    const float cc = (xx + yy) + zz;
    const float4 e = make_float4(-2.0f * cx, -2.0f * cy, -2.0f * cz, cc);
    const int p = threadIdx.x >> 1, hi = threadIdx.x & 1;
    float* a = (float*)&sA[p];
    float* b = (float*)&sB[p];
    a[0 + hi] = e.x;  a[2 + hi] = e.y;
    b[0 + hi] = e.z;  b[2 + hi] = e.w;
    if (blockIdx.x == 0) ctab[i] = e;   // persist exact bits for phase 2
  }

  const int q0 = blockIdx.x * QPB + threadIdx.x;
  f32x2 px[QPT], py[QPT], pz[QPT];
  float best[QPT];
  #pragma unroll
  for (int k = 0; k < QPT; ++k) {
    const int q = q0 + k * BLK;
    const float x = points[q * 3 + 0];
    const float y = points[q * 3 + 1];
    const float z = points[q * 3 + 2];
    px[k] = (f32x2){x, x};
    py[k] = (f32x2){y, y};
    pz[k] = (f32x2){z, z};
    best[k] = __builtin_inff();
  }
  __syncthreads();

  #pragma unroll 2
  for (int p = 0; p < TILE / 2; ++p) {
    const float4 a = sA[p];          // uniform addr -> broadcast ds_read_b128
    const float4 b = sB[p];
    const f32x2 X = {a.x, a.y}, Y = {a.z, a.w};
    const f32x2 Z = {b.x, b.y}, W = {b.z, b.w};
    #pragma unroll
    for (int k = 0; k < QPT; ++k) {
      f32x2 t = X * px[k];                             // v_pk_mul_f32 (RN)
      t = __builtin_elementwise_fma(Y, py[k], t);      // v_pk_fma_f32 (RN)
      t = __builtin_elementwise_fma(Z, pz[k], t);      // v_pk_fma_f32 (RN)
      const f32x2 d = W + t;                           // v_pk_add_f32 (RN)
      best[k] = fminf(fminf(best[k], d.x), d.y);       // v_min3_f32 (exact)
    }
  }

  #pragma unroll
  for (int k = 0; k < QPT; ++k) {
    const int q = q0 + k * BLK;
    bestd[(size_t)q * CSPLIT + s] = best[k];
  }
}

// Phase 2 (R2-proven, verbatim structure): one wave per query —
// reduce 64 split-mins (shfl min + ballot/ffs -> lowest winning split);
// equality-rescan that split's 128 coords from the SHARED global ctab (same
// bits + same frozen scalar chain as the packed halves -> hit guaranteed;
// first match = lowest coord). Tiebreak == np.argmin's global first-index.
// Then gather the 128-float feature row with 64 lanes x float2.
__global__ __launch_bounds__(256) void rescan_gather(
    const float4* __restrict__ ctab, const float* __restrict__ points,
    const float* __restrict__ bestd, const float* __restrict__ feature,
    float2* __restrict__ out) {
  const int q = blockIdx.x * 4 + (threadIdx.x >> 6);
  const int l = threadIdx.x & 63;

  // lane l holds split l's min — 256 B coalesced read per wave
  const float v = bestd[(size_t)q * CSPLIT + l];
  float m = v;
  #pragma unroll
  for (int off = 32; off; off >>= 1) m = fminf(m, __shfl_xor(m, off, 64));
  const unsigned long long bs = __ballot(v == m);
  const int sstar = __ffsll(bs) - 1;            // lowest split attaining min

  const float qx = points[q * 3 + 0];           // wave-uniform
  const float qy = points[q * 3 + 1];
  const float qz = points[q * 3 + 2];
  const int b2 = sstar * TILE;

  const float4 c0 = ctab[b2 + l];               // coalesced, lanes consecutive
  const float4 c1 = ctab[b2 + 64 + l];
  float t0 = __fmul_rn(c0.x, qx);                      // FROZEN CHAIN (R2)
  t0 = __fmaf_rn(c0.y, qy, t0);
  t0 = __fmaf_rn(c0.z, qz, t0);
  const float d0 = __fadd_rn(c0.w, t0);
  float t1 = __fmul_rn(c1.x, qx);
  t1 = __fmaf_rn(c1.y, qy, t1);
  t1 = __fmaf_rn(c1.z, qz, t1);
  const float d1 = __fadd_rn(c1.w, t1);

  const unsigned long long b0 = __ballot(d0 == m);
  const unsigned long long b1 = __ballot(d1 == m);
  int off_in;
  if (b0 | b1) {
    off_in = b0 ? (__ffsll(b0) - 1) : (64 + __ffsll(b1) - 1);
  } else {
    // Defense in depth (should be unreachable): true argmin over the 128
    // rescanned candidates, first-index tiebreak.
    float dm = fminf(d0, d1);
    int im = (d0 <= d1) ? l : (64 + l);
    #pragma unroll
    for (int off = 32; off; off >>= 1) {
      const float od = __shfl_xor(dm, off, 64);
      const int oi = __shfl_xor(im, off, 64);
      if (od < dm || (od == dm && oi < im)) { dm = od; im = oi; }
    }
    off_in = im;
  }
  const int idx = b2 + off_in;

  const float2* fr = (const float2*)(feature + (size_t)idx * CFEAT);
  out[(size_t)q * (CFEAT / 2) + l] = fr[l];
}

extern "C" void kernel_launch(void* const* d_in, const int* in_sizes, int n_in,
                              void* d_out, int out_size, void* d_ws, size_t ws_size,
                              hipStream_t stream) {
  const float* coords  = (const float*)d_in[0];   // [8192, 3]
  const float* feature = (const float*)d_in[1];   // [8192, 128]
  const float* points  = (const float*)d_in[2];   // [32768, 3]
  float2* out = (float2*)d_out;                   // [32768, 128]

  float* bestd = (float*)((char*)d_ws + BESTD_OFF);
  float4* ctab = (float4*)((char*)d_ws + CTAB_OFF);

  dim3 grid1(GX, CSPLIT);                         // (32, 64) = 2048 blocks
  argmin_split<<<grid1, BLK, 0, stream>>>(coords, points, bestd, ctab);

  rescan_gather<<<NQ / 4, 256, 0, stream>>>(ctab, points, bestd, feature,
                                            out);
}